// Round 2
// baseline (1479.536 us; speedup 1.0000x reference)
//
#include <hip/hip_runtime.h>
#include <hip/hip_bf16.h>

#define EPSN 1e-12f

__device__ __forceinline__ float rdlane(float v, int k) {
    return __int_as_float(__builtin_amdgcn_readlane(__float_as_int(v), k));
}

__device__ __forceinline__ float preluf(float x, float a) {
    return x >= 0.0f ? x : a * x;
}

// K1: in_feat = feat_z @ weight (anchor rows zeroed in output), plus
// anchor branch: out_anchor = l2norm(prelu(feat_anchor @ weight + bias)).
// wave-per-row; lane j holds weight[:,j] in 128 VGPRs; row elements
// broadcast to all lanes via v_readlane (k is unroll-constant -> SGPR).
__global__ __launch_bounds__(256) void k_transform(
    const float* __restrict__ feat, const float* __restrict__ weight,
    const float* __restrict__ bias, const float* __restrict__ prelu_a,
    float* __restrict__ in_feat, float* __restrict__ out_anchor,
    int N, int totalWaves)
{
    const int lane = threadIdx.x & 63;
    const int wid = (int)((blockIdx.x * (size_t)blockDim.x + threadIdx.x) >> 6);

    float wreg[128];
    #pragma unroll
    for (int k = 0; k < 128; ++k) wreg[k] = weight[k * 64 + lane];
    const float bj = bias[lane];
    const float a  = prelu_a[0];

    for (int row = wid; row < N; row += totalWaves) {
        const float* rp = feat + (size_t)row * 128;
        float r0 = rp[lane];        // coalesced 256B
        float r1 = rp[64 + lane];
        float acc = 0.0f;
        #pragma unroll
        for (int k = 0; k < 64; ++k) acc = fmaf(rdlane(r0, k), wreg[k], acc);
        #pragma unroll
        for (int k = 0; k < 64; ++k) acc = fmaf(rdlane(r1, k), wreg[64 + k], acc);

        if ((row & 3) == 0) {
            // anchor row: uses UN-zeroed feat; in_feat gets 0 (feat_z semantics)
            float y = preluf(acc + bj, a);
            float s = y * y;
            #pragma unroll
            for (int off = 32; off >= 1; off >>= 1) s += __shfl_xor(s, off, 64);
            float dn = fmaxf(sqrtf(s), EPSN);
            out_anchor[(size_t)(row >> 2) * 64 + lane] = y / dn;
            in_feat[(size_t)row * 64 + lane] = 0.0f;
        } else {
            in_feat[(size_t)row * 64 + lane] = acc;
        }
    }
}

// K2: h[dst] += in_feat[src] * w   (segment_sum over edges)
// wave-per-edge; 64 consecutive lanes -> coalesced gather + coalesced atomics.
__global__ __launch_bounds__(256) void k_edges(
    const float* __restrict__ in_feat, const int* __restrict__ esrc,
    const int* __restrict__ edst, const float* __restrict__ ew,
    float* __restrict__ h, int E)
{
    int wid = (int)((blockIdx.x * (size_t)blockDim.x + threadIdx.x) >> 6);
    wid = __builtin_amdgcn_readfirstlane(wid);   // force SGPR -> scalar loads of edge data
    const int lane = threadIdx.x & 63;
    if (wid >= E) return;
    const int   s = esrc[wid];
    const int   d = edst[wid];
    const float w = ew[wid];
    const float v = in_feat[((size_t)s << 6) + lane] * w;
    atomicAdd(h + ((size_t)d << 6) + lane, v);
}

// K3: h -> prelu(h+bias); pool=mean of 4 rows; gcn=row0;
// out_sub = l2norm(pool @ w_sub^T + b_sub), out_gcn = l2norm(gcn @ w_gcn^T + b_gcn)
// wave-per-group; w_sub/w_gcn rows held in 64+64 VGPRs per lane.
__global__ __launch_bounds__(256) void k_finalize(
    const float* __restrict__ h, const float* __restrict__ bias,
    const float* __restrict__ prelu_a,
    const float* __restrict__ w_sub, const float* __restrict__ b_sub,
    const float* __restrict__ w_gcn, const float* __restrict__ b_gcn,
    float* __restrict__ out_sub, float* __restrict__ out_gcn,
    int G, int totalWaves)
{
    const int lane = threadIdx.x & 63;
    const int wid = (int)((blockIdx.x * (size_t)blockDim.x + threadIdx.x) >> 6);

    float wsreg[64], wgreg[64];
    #pragma unroll
    for (int k = 0; k < 64; ++k) wsreg[k] = w_sub[lane * 64 + k];
    #pragma unroll
    for (int k = 0; k < 64; ++k) wgreg[k] = w_gcn[lane * 64 + k];
    const float bj  = bias[lane];
    const float bsj = b_sub[lane];
    const float bgj = b_gcn[lane];
    const float a   = prelu_a[0];

    for (int g = wid; g < G; g += totalWaves) {
        const float* hp = h + (size_t)g * 256;
        float p0 = preluf(hp[lane]       + bj, a);
        float p1 = preluf(hp[64  + lane] + bj, a);
        float p2 = preluf(hp[128 + lane] + bj, a);
        float p3 = preluf(hp[192 + lane] + bj, a);
        float pool = (p0 + p1 + p2 + p3) * 0.25f;
        float gcn  = p0;

        float as = bsj, ag = bgj;
        #pragma unroll
        for (int k = 0; k < 64; ++k) {
            as = fmaf(rdlane(pool, k), wsreg[k], as);
            ag = fmaf(rdlane(gcn,  k), wgreg[k], ag);
        }
        float ss = as * as, sg = ag * ag;
        #pragma unroll
        for (int off = 32; off >= 1; off >>= 1) {
            ss += __shfl_xor(ss, off, 64);
            sg += __shfl_xor(sg, off, 64);
        }
        out_sub[(size_t)g * 64 + lane] = as / fmaxf(sqrtf(ss), EPSN);
        out_gcn[(size_t)g * 64 + lane] = ag / fmaxf(sqrtf(sg), EPSN);
    }
}

extern "C" void kernel_launch(void* const* d_in, const int* in_sizes, int n_in,
                              void* d_out, int out_size, void* d_ws, size_t ws_size,
                              hipStream_t stream)
{
    const float* feat    = (const float*)d_in[0];
    const int*   esrc    = (const int*)  d_in[1];
    const int*   edst    = (const int*)  d_in[2];
    const float* ew      = (const float*)d_in[3];
    const float* weight  = (const float*)d_in[4];
    const float* bias    = (const float*)d_in[5];
    const float* prelu_a = (const float*)d_in[6];
    const float* w_sub   = (const float*)d_in[7];
    const float* b_sub   = (const float*)d_in[8];
    const float* w_gcn   = (const float*)d_in[9];
    const float* b_gcn   = (const float*)d_in[10];

    const int N = in_sizes[0] / 128;
    const int E = in_sizes[1];
    const int G = N / 4;

    float* in_feat = (float*)d_ws;                 // N*64 fp32
    float* h       = in_feat + (size_t)N * 64;     // N*64 fp32

    float* out        = (float*)d_out;
    float* out_sub    = out;                          // [0, G*64)
    float* out_anchor = out + (size_t)G * 64;         // [G*64, 2G*64)
    float* out_gcn    = out + (size_t)2 * G * 64;     // [2G*64, 3G*64)

    // h must be zeroed every launch (ws re-poisoned to 0xAA)
    hipMemsetAsync(h, 0, (size_t)N * 64 * sizeof(float), stream);

    {   // K1: 4096 waves, 64 rows each (grid-stride)
        const int blocks = 1024, tw = blocks * 4;
        k_transform<<<blocks, 256, 0, stream>>>(feat, weight, bias, prelu_a,
                                                in_feat, out_anchor, N, tw);
    }
    {   // K2: one wave per edge
        const int blocks = (E + 3) / 4;
        k_edges<<<blocks, 256, 0, stream>>>(in_feat, esrc, edst, ew, h, E);
    }
    {   // K3: 8192 waves, 8 groups each
        const int blocks = 2048, tw = blocks * 4;
        k_finalize<<<blocks, 256, 0, stream>>>(h, bias, prelu_a, w_sub, b_sub,
                                               w_gcn, b_gcn, out_sub, out_gcn, G, tw);
    }
}

// Round 3
// 1316.396 us; speedup vs baseline: 1.1239x; 1.1239x over previous
//
#include <hip/hip_runtime.h>
#include <hip/hip_bf16.h>

#define EPSN 1e-12f

__device__ __forceinline__ float rdlane(float v, int k) {
    return __int_as_float(__builtin_amdgcn_readlane(__float_as_int(v), k));
}

__device__ __forceinline__ float preluf(float x, float a) {
    return x >= 0.0f ? x : a * x;
}

// K1: in_feat = feat_z @ weight (anchor rows zeroed in output), plus
// anchor branch: out_anchor = l2norm(prelu(feat_anchor @ weight + bias)).
// wave-per-row; lane j holds weight[:,j] in 128 VGPRs; row elements
// broadcast via v_readlane. Dual accumulators halve the FMA dep-chain.
__global__ __launch_bounds__(256) void k_transform(
    const float* __restrict__ feat, const float* __restrict__ weight,
    const float* __restrict__ bias, const float* __restrict__ prelu_a,
    float* __restrict__ in_feat, float* __restrict__ out_anchor,
    int N, int totalWaves)
{
    const int lane = threadIdx.x & 63;
    const int wid = (int)((blockIdx.x * (size_t)blockDim.x + threadIdx.x) >> 6);

    float wreg[128];
    #pragma unroll
    for (int k = 0; k < 128; ++k) wreg[k] = weight[k * 64 + lane];
    const float bj = bias[lane];
    const float a  = prelu_a[0];

    for (int row = wid; row < N; row += totalWaves) {
        const float* rp = feat + (size_t)row * 128;
        float r0 = rp[lane];        // coalesced 256B
        float r1 = rp[64 + lane];
        float acc0 = 0.0f, acc1 = 0.0f;
        #pragma unroll
        for (int k = 0; k < 64; ++k) {
            acc0 = fmaf(rdlane(r0, k), wreg[k],      acc0);
            acc1 = fmaf(rdlane(r1, k), wreg[64 + k], acc1);
        }
        float acc = acc0 + acc1;

        if ((row & 3) == 0) {
            // anchor row: uses UN-zeroed feat; in_feat gets 0 (feat_z semantics)
            float y = preluf(acc + bj, a);
            float s = y * y;
            #pragma unroll
            for (int off = 32; off >= 1; off >>= 1) s += __shfl_xor(s, off, 64);
            float dn = fmaxf(sqrtf(s), EPSN);
            out_anchor[(size_t)(row >> 2) * 64 + lane] = y / dn;
            in_feat[(size_t)row * 64 + lane] = 0.0f;
        } else {
            in_feat[(size_t)row * 64 + lane] = acc;
        }
    }
}

// K2: h[dst] += in_feat[src] * w   (segment_sum over edges)
// Each wave owns a contiguous chunk; U=8 edges/iteration:
// scalar edge loads -> 8 independent gathers -> 8 atomics. MLP = 8.
#define K2_U 8
__global__ __launch_bounds__(256) void k_edges(
    const float* __restrict__ in_feat, const int* __restrict__ esrc,
    const int* __restrict__ edst, const float* __restrict__ ew,
    float* __restrict__ h, int E, int totalWaves)
{
    const int lane = threadIdx.x & 63;
    int wid = (int)((blockIdx.x * (size_t)blockDim.x + threadIdx.x) >> 6);
    wid = __builtin_amdgcn_readfirstlane(wid);

    const int chunk = (E + totalWaves - 1) / totalWaves;
    int e0 = wid * chunk;
    int e1 = min(e0 + chunk, E);

    for (int base = e0; base < e1; base += K2_U) {
        const int nb = min(K2_U, e1 - base);
        int   s[K2_U], d[K2_U];
        float w[K2_U];
        #pragma unroll
        for (int j = 0; j < K2_U; ++j) {
            int idx = base + ((j < nb) ? j : 0);   // clamp; duplicates masked below
            s[j] = esrc[idx];
            d[j] = edst[idx];
            w[j] = ew[idx];
        }
        float v[K2_U];
        #pragma unroll
        for (int j = 0; j < K2_U; ++j)
            v[j] = in_feat[((size_t)s[j] << 6) + lane];
        #pragma unroll
        for (int j = 0; j < K2_U; ++j) {
            if (j < nb)
                atomicAdd(h + ((size_t)d[j] << 6) + lane, v[j] * w[j]);
        }
    }
}

// K3: h -> prelu(h+bias); pool=mean of 4 rows; gcn=row0;
// out_sub = l2norm(pool @ w_sub^T + b_sub), out_gcn = l2norm(gcn @ w_gcn^T + b_gcn)
// wave-per-group; w_sub/w_gcn rows held in 64+64 VGPRs per lane.
__global__ __launch_bounds__(256) void k_finalize(
    const float* __restrict__ h, const float* __restrict__ bias,
    const float* __restrict__ prelu_a,
    const float* __restrict__ w_sub, const float* __restrict__ b_sub,
    const float* __restrict__ w_gcn, const float* __restrict__ b_gcn,
    float* __restrict__ out_sub, float* __restrict__ out_gcn,
    int G, int totalWaves)
{
    const int lane = threadIdx.x & 63;
    const int wid = (int)((blockIdx.x * (size_t)blockDim.x + threadIdx.x) >> 6);

    float wsreg[64], wgreg[64];
    #pragma unroll
    for (int k = 0; k < 64; ++k) wsreg[k] = w_sub[lane * 64 + k];
    #pragma unroll
    for (int k = 0; k < 64; ++k) wgreg[k] = w_gcn[lane * 64 + k];
    const float bj  = bias[lane];
    const float bsj = b_sub[lane];
    const float bgj = b_gcn[lane];
    const float a   = prelu_a[0];

    for (int g = wid; g < G; g += totalWaves) {
        const float* hp = h + (size_t)g * 256;
        float p0 = preluf(hp[lane]       + bj, a);
        float p1 = preluf(hp[64  + lane] + bj, a);
        float p2 = preluf(hp[128 + lane] + bj, a);
        float p3 = preluf(hp[192 + lane] + bj, a);
        float pool = (p0 + p1 + p2 + p3) * 0.25f;
        float gcn  = p0;

        float as = bsj, ag = bgj;
        #pragma unroll
        for (int k = 0; k < 64; ++k) {
            as = fmaf(rdlane(pool, k), wsreg[k], as);
            ag = fmaf(rdlane(gcn,  k), wgreg[k], ag);
        }
        float ss = as * as, sg = ag * ag;
        #pragma unroll
        for (int off = 32; off >= 1; off >>= 1) {
            ss += __shfl_xor(ss, off, 64);
            sg += __shfl_xor(sg, off, 64);
        }
        out_sub[(size_t)g * 64 + lane] = as / fmaxf(sqrtf(ss), EPSN);
        out_gcn[(size_t)g * 64 + lane] = ag / fmaxf(sqrtf(sg), EPSN);
    }
}

extern "C" void kernel_launch(void* const* d_in, const int* in_sizes, int n_in,
                              void* d_out, int out_size, void* d_ws, size_t ws_size,
                              hipStream_t stream)
{
    const float* feat    = (const float*)d_in[0];
    const int*   esrc    = (const int*)  d_in[1];
    const int*   edst    = (const int*)  d_in[2];
    const float* ew      = (const float*)d_in[3];
    const float* weight  = (const float*)d_in[4];
    const float* bias    = (const float*)d_in[5];
    const float* prelu_a = (const float*)d_in[6];
    const float* w_sub   = (const float*)d_in[7];
    const float* b_sub   = (const float*)d_in[8];
    const float* w_gcn   = (const float*)d_in[9];
    const float* b_gcn   = (const float*)d_in[10];

    const int N = in_sizes[0] / 128;
    const int E = in_sizes[1];
    const int G = N / 4;

    float* in_feat = (float*)d_ws;                 // N*64 fp32
    float* h       = in_feat + (size_t)N * 64;     // N*64 fp32

    float* out        = (float*)d_out;
    float* out_sub    = out;                          // [0, G*64)
    float* out_anchor = out + (size_t)G * 64;         // [G*64, 2G*64)
    float* out_gcn    = out + (size_t)2 * G * 64;     // [2G*64, 3G*64)

    // h must be zeroed every launch (ws re-poisoned to 0xAA)
    hipMemsetAsync(h, 0, (size_t)N * 64 * sizeof(float), stream);

    {   // K1: 8192 waves, 32 rows each (grid-stride)
        const int blocks = 2048, tw = blocks * 4;
        k_transform<<<blocks, 256, 0, stream>>>(feat, weight, bias, prelu_a,
                                                in_feat, out_anchor, N, tw);
    }
    {   // K2: 8192 waves, contiguous chunks, 8-edge MLP batches
        const int blocks = 2048, tw = blocks * 4;
        k_edges<<<blocks, 256, 0, stream>>>(in_feat, esrc, edst, ew, h, E, tw);
    }
    {   // K3: 16384 waves, 4 groups each
        const int blocks = 4096, tw = blocks * 4;
        k_finalize<<<blocks, 256, 0, stream>>>(h, bias, prelu_a, w_sub, b_sub,
                                               w_gcn, b_gcn, out_sub, out_gcn, G, tw);
    }
}